// Round 26
// baseline (1127.174 us; speedup 1.0000x reference)
//
#include <hip/hip_runtime.h>
#include <math.h>

#define AA 32
#define BB 2048
#define BP1 2049
#define CC 256
#define NROWS (AA * BP1)          // 65568
#define NBLK 3
#define FFN 1024

typedef unsigned int uint;
typedef unsigned short ushort_t;
typedef __attribute__((ext_vector_type(4))) float f32x4;
typedef __attribute__((ext_vector_type(8))) short short8;

// epilogue flag bits for mm_k (wave-uniform runtime flags)
#define F_ROWMAP 2
#define F_BIAS2D 4
#define F_BIAS1D 8
#define F_GELU   16
#define F_RESID  32
#define F_OUTB16 64
#define F_QKV    128

__device__ __forceinline__ float bf2f(ushort_t u) {
    return __uint_as_float(((uint)u) << 16);
}
__device__ __forceinline__ ushort_t f2b(float x) {   // fp32 -> bf16 RNE
    uint u = __float_as_uint(x);
    u += 0x7fff + ((u >> 16) & 1);
    return (ushort_t)(u >> 16);
}
// pack two fp32 -> {lo: bf16(a), hi: bf16(b)} in ONE instruction (gfx950)
__device__ __forceinline__ uint cvtpk(float a, float b) {
    uint r;
    asm("v_cvt_pk_bf16_f32 %0, %1, %2" : "=v"(r) : "v"(a), "v"(b));
    return r;
}

// global -> LDS direct 16B load
typedef const uint __attribute__((address_space(1)))* gas_t;
typedef uint __attribute__((address_space(3)))* las_t;
__device__ __forceinline__ void gload16(const ushort_t* g, const short* l) {
    __builtin_amdgcn_global_load_lds(
        reinterpret_cast<gas_t>(reinterpret_cast<uintptr_t>(g)),
        reinterpret_cast<las_t>(static_cast<uint>(reinterpret_cast<uintptr_t>(l))),
        16, 0, 0);
}

// ---------------- fp32 -> bf16 plane (hi only) ----------------
__global__ __launch_bounds__(256) void pack2_k(const float* __restrict__ src,
                                               ushort_t* __restrict__ dh, int n) {
    int i = blockIdx.x * 256 + threadIdx.x;
    if (i < n) dh[i] = f2b(src[i]);
}

// ---------------- Wqkv pack with head-interleaved q/k rows (hi plane only) ----------------
// dst row order per layer: [h0q(32) h0k(32) ... h7q h7k, v(256)]
__global__ __launch_bounds__(256) void wqkv_pack_k(const float* __restrict__ src,
                                                   ushort_t* __restrict__ dh) {
    int i = blockIdx.x * 256 + threadIdx.x;      // 589,824 total
    if (i >= 589824) return;
    int c = i & 255;
    int rr = (i >> 8) % 768;
    int a = i / (768 * 256);
    int srcrow;
    if (rr < 512) {
        int head = rr >> 6, half = (rr >> 5) & 1, d = rr & 31;
        srcrow = half * 256 + head * 32 + d;
    } else {
        srcrow = rr;
    }
    dh[i] = f2b(src[((size_t)a * 768 + srcrow) * 256 + c]);
}

// ---------------- row 0 of each batch: cls + bias ----------------
__global__ __launch_bounds__(256) void row0_k(float* __restrict__ out,
                                              const float* __restrict__ cls,
                                              const float* __restrict__ bias) {
    int i = blockIdx.x, t = threadIdx.x;
    size_t o = (size_t)i * BP1 * CC + t;
    out[o] = cls[i * CC + t] + bias[o];
}

// ---------------- layernorm f32 -> bf16 plane (hi only, cvt_pk packed) ----------------
__global__ __launch_bounds__(256) void ln_k(const float* __restrict__ in,
                                            ushort_t* __restrict__ zh,
                                            const float* __restrict__ g, const float* __restrict__ b) {
    int row = blockIdx.x * 4 + (threadIdx.x >> 6);
    int lane = threadIdx.x & 63;
    const float4 v = *reinterpret_cast<const float4*>(in + (size_t)row * CC + lane * 4);
    float s = v.x + v.y + v.z + v.w;
    float sq = v.x * v.x + v.y * v.y + v.z * v.z + v.w * v.w;
    #pragma unroll
    for (int m = 1; m < 64; m <<= 1) { s += __shfl_xor(s, m); sq += __shfl_xor(sq, m); }
    float mu = s * (1.0f / CC);
    float var = sq * (1.0f / CC) - mu * mu;
    float rs = rsqrtf(var + 1e-5f);
    const float4 gg = *reinterpret_cast<const float4*>(g + lane * 4);
    const float4 bb = *reinterpret_cast<const float4*>(b + lane * 4);
    float o0 = (v.x - mu) * rs * gg.x + bb.x;
    float o1 = (v.y - mu) * rs * gg.y + bb.y;
    float o2 = (v.z - mu) * rs * gg.z + bb.z;
    float o3 = (v.w - mu) * rs * gg.w + bb.w;
    uint2 u;
    u.x = cvtpk(o0, o1);
    u.y = cvtpk(o2, o3);
    *reinterpret_cast<uint2*>(zh + (size_t)row * CC + lane * 4) = u;
}

// ---------------- cumsum pass 1: per-chunk totals of rsa*v (v bf16, 64 chunks x 32 rows) ----------------
__global__ __launch_bounds__(256) void cumsum1_k(const ushort_t* __restrict__ v,
                                                 const float* __restrict__ rsa,
                                                 float* __restrict__ tot) {
    int bi = blockIdx.x >> 6, ch = blockIdx.x & 63, c = threadIdx.x;
    int h = c >> 5;
    size_t row0 = (size_t)bi * BP1 + ch * 32;
    float s = 0.f;
    for (int j = 0; j < 32; ++j)
        s += bf2f(v[(row0 + j) * CC + c]) * rsa[(row0 + j) * 8 + h];
    tot[((size_t)bi * 64 + ch) * CC + c] = s;
}

// ---------------- cumsum pass 2: scan rsa*v + offset -> im hi plane only ----------------
__global__ __launch_bounds__(256) void cumsum2_k(const ushort_t* __restrict__ v,
                                                 const float* __restrict__ rsa,
                                                 const float* __restrict__ tot,
                                                 ushort_t* __restrict__ ph) {
    int bi = blockIdx.x / 65, ch = blockIdx.x - bi * 65, c = threadIdx.x;
    int h = c >> 5;
    if (ch == 64) {   // row BB (untouched by cumsum): scale + pack
        size_t row = (size_t)bi * BP1 + BB;
        float val = bf2f(v[row * CC + c]) * rsa[row * 8 + h];
        ph[row * CC + c] = f2b(val);
        return;
    }
    float s = 0.f;
    for (int q = 0; q < ch; ++q) s += tot[((size_t)bi * 64 + q) * CC + c];
    size_t row0 = (size_t)bi * BP1 + ch * 32;
    for (int j = 0; j < 32; ++j) {
        size_t row = row0 + j;
        s += bf2f(v[row * CC + c]) * rsa[row * 8 + h];
        ph[row * CC + c] = f2b(s);
    }
}

// ---------------- split-bf16 MFMA GEMM, 1-wave 64x64 tile, barrier-free (r20 base) ----------------
// Out(MxN) = A(MxK) * W(NxK)^T ; 1-D grid = NT*MT (MT = M/64, NT = NC/64).
// Wave stages its own tiles via global_load_lds; sync is wave-private s_waitcnt vmcnt(0).
// MFMA operand-swapped: lane holds Out[row = m0+i*16+(l&15)][4 consecutive cols].
template<int ALO, int WLO>
__global__ __launch_bounds__(64) void mm_k(const ushort_t* __restrict__ Ah_g,
                                           const ushort_t* __restrict__ Al_g,
                                           const ushort_t* __restrict__ Bh_g,
                                           const ushort_t* __restrict__ Bl_g,
                                           void* __restrict__ Op,
                                           void* __restrict__ Op2,
                                           const float* __restrict__ bias,
                                           int M, int K, int NC, int NT, int flags) {
    __shared__ __align__(16) short As_h[2048];
    __shared__ __align__(16) short As_l[ALO ? 2048 : 8];
    __shared__ __align__(16) short Bs_h[2048];
    __shared__ __align__(16) short Bs_l[WLO ? 2048 : 8];
    const int l = threadIdx.x;                     // 0..63 (one wave)

    // XCD-bijective block swizzle (m204)
    const int nwg = gridDim.x;
    const int q8 = nwg >> 3, r8 = nwg & 7;
    const int xcd = blockIdx.x & 7, ii = blockIdx.x >> 3;
    const int wgid = (xcd < r8 ? xcd * (q8 + 1) : r8 * (q8 + 1) + (xcd - r8) * q8) + ii;
    const int nt = wgid % NT, mt = wgid / NT;
    const int n0 = nt * 64, m0 = mt * 64;

    // staging: chunk c covers rows c*16 + (l>>2), cols (l&3)*8 (1 KB per chunk)
    const int sc = (l & 3) * 8;
    const int lr = l >> 2;
    size_t aoff[4], boff[4];
    #pragma unroll
    for (int c = 0; c < 4; ++c) {
        int ra = m0 + c * 16 + lr; if (ra >= M) ra = M - 1;
        aoff[c] = (size_t)ra * K + sc;
        boff[c] = (size_t)(n0 + c * 16 + lr) * K + sc;
    }

    f32x4 acc[4][4];
    #pragma unroll
    for (int i = 0; i < 4; ++i)
        #pragma unroll
        for (int j = 0; j < 4; ++j) acc[i][j] = (f32x4)(0.0f);

    for (int k0 = 0; k0 < K; k0 += 32) {
        #pragma unroll
        for (int c = 0; c < 4; ++c) {
            gload16(Ah_g + aoff[c] + k0, &As_h[c * 512]);
            if (ALO) gload16(Al_g + aoff[c] + k0, &As_l[c * 512]);
            gload16(Bh_g + boff[c] + k0, &Bs_h[c * 512]);
            if (WLO) gload16(Bl_g + boff[c] + k0, &Bs_l[c * 512]);
        }
        asm volatile("s_waitcnt vmcnt(0)" ::: "memory");   // wave-private drain
        __builtin_amdgcn_sched_barrier(0);                 // rule #18 fence
        short8 ah[4], al[4], bh[4], bl[4];
        #pragma unroll
        for (int i = 0; i < 4; ++i) {
            int ro = (i * 16 + (l & 15)) * 32 + (l >> 4) * 8;
            ah[i] = *reinterpret_cast<const short8*>(&As_h[ro]);
            if (ALO) al[i] = *reinterpret_cast<const short8*>(&As_l[ro]);
        }
        #pragma unroll
        for (int j = 0; j < 4; ++j) {
            int ro = (j * 16 + (l & 15)) * 32 + (l >> 4) * 8;
            bh[j] = *reinterpret_cast<const short8*>(&Bs_h[ro]);
            if (WLO) bl[j] = *reinterpret_cast<const short8*>(&Bs_l[ro]);
        }
        // operand-swapped MFMA: D = B-frag x A-frag
        __builtin_amdgcn_s_setprio(1);
        #pragma unroll
        for (int i = 0; i < 4; ++i)
            #pragma unroll
            for (int j = 0; j < 4; ++j) {
                acc[i][j] = __builtin_amdgcn_mfma_f32_16x16x32_bf16(bh[j], ah[i], acc[i][j], 0, 0, 0);
                if (WLO)
                    acc[i][j] = __builtin_amdgcn_mfma_f32_16x16x32_bf16(bl[j], ah[i], acc[i][j], 0, 0, 0);
                if (ALO)
                    acc[i][j] = __builtin_amdgcn_mfma_f32_16x16x32_bf16(bh[j], al[i], acc[i][j], 0, 0, 0);
            }
        __builtin_amdgcn_s_setprio(0);
        __builtin_amdgcn_sched_barrier(0);   // keep next-tile staging below the MFMAs
    }

    // ---- F_QKV epilogue (swapped layout) ----
    if (flags & F_QKV) {
        const int cb0 = n0;                        // 64-wide tile = one head's q|k
        if (cb0 < 512) {
            float* rsaO = reinterpret_cast<float*>(Op);
            const int head = cb0 >> 6;
            #pragma unroll
            for (int i = 0; i < 4; ++i) {
                int row = m0 + i * 16 + (l & 15);
                float p = 0.f;
                #pragma unroll
                for (int j = 0; j < 2; ++j)
                    #pragma unroll
                    for (int r = 0; r < 4; ++r)
                        p += acc[i][j][r] * acc[i][j + 2][r];
                p += __shfl_xor(p, 16);
                p += __shfl_xor(p, 32);
                if (l < 16 && row < M)
                    rsaO[(size_t)row * 8 + head] = p * 0.17677669529663689f;
            }
        } else {                                   // v tile -> bf16 vbuf (uint2 = 4 bf16)
            ushort_t* vO = reinterpret_cast<ushort_t*>(Op2);
            #pragma unroll
            for (int i = 0; i < 4; ++i) {
                int row = m0 + i * 16 + (l & 15);
                if (row >= M) continue;
                #pragma unroll
                for (int j = 0; j < 4; ++j) {
                    int colb = cb0 + j * 16 + (l >> 4) * 4 - 512;
                    uint2 u;
                    u.x = cvtpk(acc[i][j][0], acc[i][j][1]);
                    u.y = cvtpk(acc[i][j][2], acc[i][j][3]);
                    *reinterpret_cast<uint2*>(vO + (size_t)row * 256 + colb) = u;
                }
            }
        }
        return;
    }

    // ---- general epilogue ----
    #pragma unroll
    for (int i = 0; i < 4; ++i) {
        int row = m0 + i * 16 + (l & 15);
        if (row >= M) continue;
        size_t g = (flags & F_ROWMAP) ? ((size_t)(row >> 11) * BP1 + 1 + (row & 2047))
                                     : (size_t)row;
        #pragma unroll
        for (int j = 0; j < 4; ++j) {
            int col0 = n0 + j * 16 + (l >> 4) * 4;
            float4 v4 = make_float4(acc[i][j][0], acc[i][j][1], acc[i][j][2], acc[i][j][3]);
            if (flags & F_BIAS1D) {
                const float4 b4 = *reinterpret_cast<const float4*>(bias + col0);
                v4.x += b4.x; v4.y += b4.y; v4.z += b4.z; v4.w += b4.w;
            }
            if (flags & F_BIAS2D) {
                const float4 b4 = *reinterpret_cast<const float4*>(bias + g * (size_t)NC + col0);
                v4.x += b4.x; v4.y += b4.y; v4.z += b4.z; v4.w += b4.w;
            }
            if (flags & F_GELU) {   // tanh-form GELU, fast rcp
                float z0 = v4.x * (1.595769122f + 0.071354816f * v4.x * v4.x);
                float z1 = v4.y * (1.595769122f + 0.071354816f * v4.y * v4.y);
                float z2 = v4.z * (1.595769122f + 0.071354816f * v4.z * v4.z);
                float z3 = v4.w * (1.595769122f + 0.071354816f * v4.w * v4.w);
                v4.x *= __builtin_amdgcn_rcpf(1.0f + __expf(-z0));
                v4.y *= __builtin_amdgcn_rcpf(1.0f + __expf(-z1));
                v4.z *= __builtin_amdgcn_rcpf(1.0f + __expf(-z2));
                v4.w *= __builtin_amdgcn_rcpf(1.0f + __expf(-z3));
            }
            size_t oi = g * (size_t)NC + col0;
            if (flags & F_OUTB16) {
                uint2 u;
                u.x = cvtpk(v4.x, v4.y);
                u.y = cvtpk(v4.z, v4.w);
                *reinterpret_cast<uint2*>(reinterpret_cast<ushort_t*>(Op) + oi) = u;
            } else {
                float* O = reinterpret_cast<float*>(Op) + oi;
                if (flags & F_RESID) {
                    const float4 o4 = *reinterpret_cast<const float4*>(O);
                    v4.x += o4.x; v4.y += o4.y; v4.z += o4.z; v4.w += o4.w;
                }
                *reinterpret_cast<float4*>(O) = v4;
            }
        }
    }
}

// ---------------- launch ----------------
extern "C" void kernel_launch(void* const* d_in, const int* in_sizes, int n_in,
                              void* d_out, int out_size, void* d_ws, size_t ws_size,
                              hipStream_t stream) {
    const float* x      = (const float*)d_in[0];
    const float* weight = (const float*)d_in[1];
    const float* bias   = (const float*)d_in[2];
    const float* cls    = (const float*)d_in[3];
    const float* Wqkv   = (const float*)d_in[4];
    const float* Wo     = (const float*)d_in[5];
    const float* ln1_g  = (const float*)d_in[6];
    const float* ln1_b  = (const float*)d_in[7];
    const float* ln2_g  = (const float*)d_in[8];
    const float* ln2_b  = (const float*)d_in[9];
    const float* fc1_w  = (const float*)d_in[10];
    const float* fc1_b  = (const float*)d_in[11];
    const float* fc2_w  = (const float*)d_in[12];
    const float* fc2_b  = (const float*)d_in[13];
    float* out = (float*)d_out;

    // ---- workspace (high-water 209,290,240 B — proven rounds 7-25) ----
    char* ws = (char*)d_ws;
    ushort_t* zh    = (ushort_t*)(ws + 0);
    float*    tot   = (float*)(ws + 33570816);                 // 32*64*256 f32 = 2 MB
    ushort_t* vbuf  = (ushort_t*)(ws + 67141632);
    ushort_t* imh   = (ushort_t*)(ws + 134283264);
    ushort_t* hbuf  = (ushort_t*)(ws + 67141632);              // spans R1+R2
    float*    rsa   = (float*)(ws + 201424896);
    ushort_t* wp    = (ushort_t*)(ws + 203785216);

    ushort_t* w_h    = wp;                 // weight  65,536 (hi only)
    ushort_t* wqkv_h = wp + 131072;        // Wqkv   589,824 (head-interleaved, hi only)
    ushort_t* wo_h   = wp + 1310720;       // Wo     196,608 (hi only)
    ushort_t* fc1_h  = wp + 1703936;       // fc1    262,144 (hi only)
    ushort_t* fc2_h  = wp + 2228224;       // fc2    262,144 (hi only)

    pack2_k<<<256,  256, 0, stream>>>(weight, w_h,   65536);
    wqkv_pack_k<<<2304, 256, 0, stream>>>(Wqkv, wqkv_h);
    pack2_k<<<768,  256, 0, stream>>>(Wo,     wo_h,  196608);
    pack2_k<<<1024, 256, 0, stream>>>(fc1_w,  fc1_h, 262144);
    pack2_k<<<1024, 256, 0, stream>>>(fc2_w,  fc2_h, 262144);
    // pack x hi-only into zh (consumed by embed GEMM, then ln_k overwrites)
    pack2_k<<<65536, 256, 0, stream>>>(x, zh, AA * BB * CC);

    row0_k<<<AA, 256, 0, stream>>>(out, cls, bias);
    // embed: out[i,1+j,:] = x[i,j,:] @ weight^T + bias  (1-term)
    mm_k<0,0><<<4 * 1024, 64, 0, stream>>>(zh, nullptr, w_h, nullptr, out, nullptr, bias,
                                           AA * BB, CC, CC, 4, F_ROWMAP | F_BIAS2D);

    const int MT = (NROWS + 63) / 64;   // 1025
    for (int a = 0; a < NBLK; ++a) {
        const size_t aw = (size_t)a * 196608;   // per-layer Wqkv stride
        ln_k<<<NROWS / 4, 256, 0, stream>>>(out, zh, ln1_g, ln1_b);
        // fused qkv (1-term): qk tiles -> rsa in-register (fp32), v tiles -> bf16 vbuf
        mm_k<0,0><<<12 * MT, 64, 0, stream>>>(zh, nullptr, wqkv_h + aw, nullptr,
                                              rsa, vbuf, nullptr,
                                              NROWS, CC, 768, 12, F_QKV);
        cumsum1_k<<<2048, 256, 0, stream>>>(vbuf, rsa, tot);
        cumsum2_k<<<2080, 256, 0, stream>>>(vbuf, rsa, tot, imh);
        // savespace += im @ Wo^T  (1-term: im bf16 x Wo hi)
        mm_k<0,0><<<4 * MT, 64, 0, stream>>>(imh, nullptr, wo_h + (size_t)a * 65536,
                                             nullptr, out, nullptr, nullptr,
                                             NROWS, CC, CC, 4, F_RESID);
        ln_k<<<NROWS / 4, 256, 0, stream>>>(out, zh, ln2_g, ln2_b);
        // h = gelu(z @ fc1^T + b) -> bf16 hbuf  (1-term)
        mm_k<0,0><<<16 * MT, 64, 0, stream>>>(zh, nullptr, fc1_h, nullptr, hbuf, nullptr, fc1_b,
                                              NROWS, CC, FFN, 16, F_BIAS1D | F_GELU | F_OUTB16);
        // savespace += h @ fc2^T + b  (1-term)
        mm_k<0,0><<<4 * MT, 64, 0, stream>>>(hbuf, nullptr, fc2_h, nullptr, out, nullptr, fc2_b,
                                             NROWS, FFN, CC, 4, F_BIAS1D | F_RESID);
    }
}

// Round 27
// 1120.107 us; speedup vs baseline: 1.0063x; 1.0063x over previous
//
#include <hip/hip_runtime.h>
#include <math.h>

#define AA 32
#define BB 2048
#define BP1 2049
#define CC 256
#define NROWS (AA * BP1)          // 65568
#define NBLK 3
#define FFN 1024

typedef unsigned int uint;
typedef unsigned short ushort_t;
typedef __attribute__((ext_vector_type(4))) float f32x4;
typedef __attribute__((ext_vector_type(8))) short short8;

// epilogue flag bits for mm_k (wave-uniform runtime flags)
#define F_ROWMAP 2
#define F_BIAS2D 4
#define F_BIAS1D 8
#define F_GELU   16
#define F_RESID  32
#define F_OUTB16 64
#define F_QKV    128

__device__ __forceinline__ float bf2f(ushort_t u) {
    return __uint_as_float(((uint)u) << 16);
}
__device__ __forceinline__ ushort_t f2b(float x) {   // fp32 -> bf16 RNE
    uint u = __float_as_uint(x);
    u += 0x7fff + ((u >> 16) & 1);
    return (ushort_t)(u >> 16);
}
// pack two fp32 -> {lo: bf16(a), hi: bf16(b)} in ONE instruction (gfx950)
__device__ __forceinline__ uint cvtpk(float a, float b) {
    uint r;
    asm("v_cvt_pk_bf16_f32 %0, %1, %2" : "=v"(r) : "v"(a), "v"(b));
    return r;
}

// global -> LDS direct 16B load
typedef const uint __attribute__((address_space(1)))* gas_t;
typedef uint __attribute__((address_space(3)))* las_t;
__device__ __forceinline__ void gload16(const ushort_t* g, const short* l) {
    __builtin_amdgcn_global_load_lds(
        reinterpret_cast<gas_t>(reinterpret_cast<uintptr_t>(g)),
        reinterpret_cast<las_t>(static_cast<uint>(reinterpret_cast<uintptr_t>(l))),
        16, 0, 0);
}

// ---------------- fp32 -> bf16 planes (lo plane optional) ----------------
__global__ __launch_bounds__(256) void pack2_k(const float* __restrict__ src,
                                               ushort_t* __restrict__ dh,
                                               ushort_t* __restrict__ dl, int n) {
    int i = blockIdx.x * 256 + threadIdx.x;
    if (i < n) {
        float v = src[i];
        ushort_t h = f2b(v);
        dh[i] = h;
        if (dl) dl[i] = f2b(v - bf2f(h));
    }
}

// ---------------- Wqkv pack with head-interleaved q/k rows (hi plane only) ----------------
// dst row order per layer: [h0q(32) h0k(32) ... h7q h7k, v(256)]
__global__ __launch_bounds__(256) void wqkv_pack_k(const float* __restrict__ src,
                                                   ushort_t* __restrict__ dh) {
    int i = blockIdx.x * 256 + threadIdx.x;      // 589,824 total
    if (i >= 589824) return;
    int c = i & 255;
    int rr = (i >> 8) % 768;
    int a = i / (768 * 256);
    int srcrow;
    if (rr < 512) {
        int head = rr >> 6, half = (rr >> 5) & 1, d = rr & 31;
        srcrow = half * 256 + head * 32 + d;
    } else {
        srcrow = rr;
    }
    dh[i] = f2b(src[((size_t)a * 768 + srcrow) * 256 + c]);
}

// ---------------- row 0 of each batch: cls + bias ----------------
__global__ __launch_bounds__(256) void row0_k(float* __restrict__ out,
                                              const float* __restrict__ cls,
                                              const float* __restrict__ bias) {
    int i = blockIdx.x, t = threadIdx.x;
    size_t o = (size_t)i * BP1 * CC + t;
    out[o] = cls[i * CC + t] + bias[o];
}

// ---------------- layernorm f32 -> bf16 plane (hi only, cvt_pk packed) ----------------
__global__ __launch_bounds__(256) void ln_k(const float* __restrict__ in,
                                            ushort_t* __restrict__ zh,
                                            const float* __restrict__ g, const float* __restrict__ b) {
    int row = blockIdx.x * 4 + (threadIdx.x >> 6);
    int lane = threadIdx.x & 63;
    const float4 v = *reinterpret_cast<const float4*>(in + (size_t)row * CC + lane * 4);
    float s = v.x + v.y + v.z + v.w;
    float sq = v.x * v.x + v.y * v.y + v.z * v.z + v.w * v.w;
    #pragma unroll
    for (int m = 1; m < 64; m <<= 1) { s += __shfl_xor(s, m); sq += __shfl_xor(sq, m); }
    float mu = s * (1.0f / CC);
    float var = sq * (1.0f / CC) - mu * mu;
    float rs = rsqrtf(var + 1e-5f);
    const float4 gg = *reinterpret_cast<const float4*>(g + lane * 4);
    const float4 bb = *reinterpret_cast<const float4*>(b + lane * 4);
    float o0 = (v.x - mu) * rs * gg.x + bb.x;
    float o1 = (v.y - mu) * rs * gg.y + bb.y;
    float o2 = (v.z - mu) * rs * gg.z + bb.z;
    float o3 = (v.w - mu) * rs * gg.w + bb.w;
    uint2 u;
    u.x = cvtpk(o0, o1);
    u.y = cvtpk(o2, o3);
    *reinterpret_cast<uint2*>(zh + (size_t)row * CC + lane * 4) = u;
}

// ---------------- cumsum pass 1: per-chunk totals of rsa*v (v bf16, 32 x 64 rows) ----------------
__global__ __launch_bounds__(256) void cumsum1_k(const ushort_t* __restrict__ v,
                                                 const float* __restrict__ rsa,
                                                 float* __restrict__ tot) {
    int bi = blockIdx.x >> 5, ch = blockIdx.x & 31, c = threadIdx.x;
    int h = c >> 5;
    size_t row0 = (size_t)bi * BP1 + ch * 64;
    float s = 0.f;
    for (int j = 0; j < 64; ++j)
        s += bf2f(v[(row0 + j) * CC + c]) * rsa[(row0 + j) * 8 + h];
    tot[((size_t)bi * 32 + ch) * CC + c] = s;
}

// ---------------- cumsum pass 2: scan rsa*v + offset -> im hi plane only ----------------
__global__ __launch_bounds__(256) void cumsum2_k(const ushort_t* __restrict__ v,
                                                 const float* __restrict__ rsa,
                                                 const float* __restrict__ tot,
                                                 ushort_t* __restrict__ ph) {
    int bi = blockIdx.x / 33, ch = blockIdx.x - bi * 33, c = threadIdx.x;
    int h = c >> 5;
    if (ch == 32) {
        size_t row = (size_t)bi * BP1 + BB;
        float val = bf2f(v[row * CC + c]) * rsa[row * 8 + h];
        ph[row * CC + c] = f2b(val);
        return;
    }
    float s = 0.f;
    for (int q = 0; q < ch; ++q) s += tot[((size_t)bi * 32 + q) * CC + c];
    size_t row0 = (size_t)bi * BP1 + ch * 64;
    for (int j = 0; j < 64; ++j) {
        size_t row = row0 + j;
        s += bf2f(v[row * CC + c]) * rsa[row * 8 + h];
        ph[row * CC + c] = f2b(s);
    }
}

// ---------------- split-bf16 MFMA GEMM, 1-wave 64x64 tile, barrier-free (r20 base) ----------------
// Out(MxN) = A(MxK) * W(NxK)^T ; 1-D grid = NT*MT (MT = M/64, NT = NC/64).
// Wave stages its own tiles via global_load_lds; sync is wave-private s_waitcnt vmcnt(0).
// MFMA operand-swapped: lane holds Out[row = m0+i*16+(l&15)][4 consecutive cols].
template<int ALO, int WLO>
__global__ __launch_bounds__(64) void mm_k(const ushort_t* __restrict__ Ah_g,
                                           const ushort_t* __restrict__ Al_g,
                                           const ushort_t* __restrict__ Bh_g,
                                           const ushort_t* __restrict__ Bl_g,
                                           void* __restrict__ Op,
                                           void* __restrict__ Op2,
                                           const float* __restrict__ bias,
                                           int M, int K, int NC, int NT, int flags) {
    __shared__ __align__(16) short As_h[2048];
    __shared__ __align__(16) short As_l[ALO ? 2048 : 8];
    __shared__ __align__(16) short Bs_h[2048];
    __shared__ __align__(16) short Bs_l[WLO ? 2048 : 8];
    const int l = threadIdx.x;                     // 0..63 (one wave)

    // XCD-bijective block swizzle (m204)
    const int nwg = gridDim.x;
    const int q8 = nwg >> 3, r8 = nwg & 7;
    const int xcd = blockIdx.x & 7, ii = blockIdx.x >> 3;
    const int wgid = (xcd < r8 ? xcd * (q8 + 1) : r8 * (q8 + 1) + (xcd - r8) * q8) + ii;
    const int nt = wgid % NT, mt = wgid / NT;
    const int n0 = nt * 64, m0 = mt * 64;

    // staging: chunk c covers rows c*16 + (l>>2), cols (l&3)*8 (1 KB per chunk)
    const int sc = (l & 3) * 8;
    const int lr = l >> 2;
    size_t aoff[4], boff[4];
    #pragma unroll
    for (int c = 0; c < 4; ++c) {
        int ra = m0 + c * 16 + lr; if (ra >= M) ra = M - 1;
        aoff[c] = (size_t)ra * K + sc;
        boff[c] = (size_t)(n0 + c * 16 + lr) * K + sc;
    }

    f32x4 acc[4][4];
    #pragma unroll
    for (int i = 0; i < 4; ++i)
        #pragma unroll
        for (int j = 0; j < 4; ++j) acc[i][j] = (f32x4)(0.0f);

    for (int k0 = 0; k0 < K; k0 += 32) {
        #pragma unroll
        for (int c = 0; c < 4; ++c) {
            gload16(Ah_g + aoff[c] + k0, &As_h[c * 512]);
            if (ALO) gload16(Al_g + aoff[c] + k0, &As_l[c * 512]);
            gload16(Bh_g + boff[c] + k0, &Bs_h[c * 512]);
            if (WLO) gload16(Bl_g + boff[c] + k0, &Bs_l[c * 512]);
        }
        asm volatile("s_waitcnt vmcnt(0)" ::: "memory");   // wave-private drain
        __builtin_amdgcn_sched_barrier(0);                 // rule #18 fence
        short8 ah[4], al[4], bh[4], bl[4];
        #pragma unroll
        for (int i = 0; i < 4; ++i) {
            int ro = (i * 16 + (l & 15)) * 32 + (l >> 4) * 8;
            ah[i] = *reinterpret_cast<const short8*>(&As_h[ro]);
            if (ALO) al[i] = *reinterpret_cast<const short8*>(&As_l[ro]);
        }
        #pragma unroll
        for (int j = 0; j < 4; ++j) {
            int ro = (j * 16 + (l & 15)) * 32 + (l >> 4) * 8;
            bh[j] = *reinterpret_cast<const short8*>(&Bs_h[ro]);
            if (WLO) bl[j] = *reinterpret_cast<const short8*>(&Bs_l[ro]);
        }
        // operand-swapped MFMA: D = B-frag x A-frag
        __builtin_amdgcn_s_setprio(1);
        #pragma unroll
        for (int i = 0; i < 4; ++i)
            #pragma unroll
            for (int j = 0; j < 4; ++j) {
                acc[i][j] = __builtin_amdgcn_mfma_f32_16x16x32_bf16(bh[j], ah[i], acc[i][j], 0, 0, 0);
                if (WLO)
                    acc[i][j] = __builtin_amdgcn_mfma_f32_16x16x32_bf16(bl[j], ah[i], acc[i][j], 0, 0, 0);
                if (ALO)
                    acc[i][j] = __builtin_amdgcn_mfma_f32_16x16x32_bf16(bh[j], al[i], acc[i][j], 0, 0, 0);
            }
        __builtin_amdgcn_s_setprio(0);
        __builtin_amdgcn_sched_barrier(0);   // keep next-tile staging below the MFMAs
    }

    // ---- F_QKV epilogue (swapped layout) ----
    if (flags & F_QKV) {
        const int cb0 = n0;                        // 64-wide tile = one head's q|k
        if (cb0 < 512) {
            float* rsaO = reinterpret_cast<float*>(Op);
            const int head = cb0 >> 6;
            #pragma unroll
            for (int i = 0; i < 4; ++i) {
                int row = m0 + i * 16 + (l & 15);
                float p = 0.f;
                #pragma unroll
                for (int j = 0; j < 2; ++j)
                    #pragma unroll
                    for (int r = 0; r < 4; ++r)
                        p += acc[i][j][r] * acc[i][j + 2][r];
                p += __shfl_xor(p, 16);
                p += __shfl_xor(p, 32);
                if (l < 16 && row < M)
                    rsaO[(size_t)row * 8 + head] = p * 0.17677669529663689f;
            }
        } else {                                   // v tile -> bf16 vbuf (uint2 = 4 bf16)
            ushort_t* vO = reinterpret_cast<ushort_t*>(Op2);
            #pragma unroll
            for (int i = 0; i < 4; ++i) {
                int row = m0 + i * 16 + (l & 15);
                if (row >= M) continue;
                #pragma unroll
                for (int j = 0; j < 4; ++j) {
                    int colb = cb0 + j * 16 + (l >> 4) * 4 - 512;
                    uint2 u;
                    u.x = cvtpk(acc[i][j][0], acc[i][j][1]);
                    u.y = cvtpk(acc[i][j][2], acc[i][j][3]);
                    *reinterpret_cast<uint2*>(vO + (size_t)row * 256 + colb) = u;
                }
            }
        }
        return;
    }

    // ---- general epilogue ----
    #pragma unroll
    for (int i = 0; i < 4; ++i) {
        int row = m0 + i * 16 + (l & 15);
        if (row >= M) continue;
        size_t g = (flags & F_ROWMAP) ? ((size_t)(row >> 11) * BP1 + 1 + (row & 2047))
                                     : (size_t)row;
        #pragma unroll
        for (int j = 0; j < 4; ++j) {
            int col0 = n0 + j * 16 + (l >> 4) * 4;
            float4 v4 = make_float4(acc[i][j][0], acc[i][j][1], acc[i][j][2], acc[i][j][3]);
            if (flags & F_BIAS1D) {
                const float4 b4 = *reinterpret_cast<const float4*>(bias + col0);
                v4.x += b4.x; v4.y += b4.y; v4.z += b4.z; v4.w += b4.w;
            }
            if (flags & F_BIAS2D) {
                const float4 b4 = *reinterpret_cast<const float4*>(bias + g * (size_t)NC + col0);
                v4.x += b4.x; v4.y += b4.y; v4.z += b4.z; v4.w += b4.w;
            }
            if (flags & F_GELU) {   // tanh-form GELU, fast rcp
                float z0 = v4.x * (1.595769122f + 0.071354816f * v4.x * v4.x);
                float z1 = v4.y * (1.595769122f + 0.071354816f * v4.y * v4.y);
                float z2 = v4.z * (1.595769122f + 0.071354816f * v4.z * v4.z);
                float z3 = v4.w * (1.595769122f + 0.071354816f * v4.w * v4.w);
                v4.x *= __builtin_amdgcn_rcpf(1.0f + __expf(-z0));
                v4.y *= __builtin_amdgcn_rcpf(1.0f + __expf(-z1));
                v4.z *= __builtin_amdgcn_rcpf(1.0f + __expf(-z2));
                v4.w *= __builtin_amdgcn_rcpf(1.0f + __expf(-z3));
            }
            size_t oi = g * (size_t)NC + col0;
            if (flags & F_OUTB16) {
                uint2 u;
                u.x = cvtpk(v4.x, v4.y);
                u.y = cvtpk(v4.z, v4.w);
                *reinterpret_cast<uint2*>(reinterpret_cast<ushort_t*>(Op) + oi) = u;
            } else {
                float* O = reinterpret_cast<float*>(Op) + oi;
                if (flags & F_RESID) {
                    const float4 o4 = *reinterpret_cast<const float4*>(O);
                    v4.x += o4.x; v4.y += o4.y; v4.z += o4.z; v4.w += o4.w;
                }
                *reinterpret_cast<float4*>(O) = v4;
            }
        }
    }
}

// ---------------- launch ----------------
extern "C" void kernel_launch(void* const* d_in, const int* in_sizes, int n_in,
                              void* d_out, int out_size, void* d_ws, size_t ws_size,
                              hipStream_t stream) {
    const float* x      = (const float*)d_in[0];
    const float* weight = (const float*)d_in[1];
    const float* bias   = (const float*)d_in[2];
    const float* cls    = (const float*)d_in[3];
    const float* Wqkv   = (const float*)d_in[4];
    const float* Wo     = (const float*)d_in[5];
    const float* ln1_g  = (const float*)d_in[6];
    const float* ln1_b  = (const float*)d_in[7];
    const float* ln2_g  = (const float*)d_in[8];
    const float* ln2_b  = (const float*)d_in[9];
    const float* fc1_w  = (const float*)d_in[10];
    const float* fc1_b  = (const float*)d_in[11];
    const float* fc2_w  = (const float*)d_in[12];
    const float* fc2_b  = (const float*)d_in[13];
    float* out = (float*)d_out;

    // ---- workspace (high-water 209,290,240 B — proven rounds 7-26) ----
    char* ws = (char*)d_ws;
    ushort_t* zh    = (ushort_t*)(ws + 0);
    float*    tot   = (float*)(ws + 33570816);
    ushort_t* vbuf  = (ushort_t*)(ws + 67141632);
    ushort_t* imh   = (ushort_t*)(ws + 134283264);
    ushort_t* hbuf  = (ushort_t*)(ws + 67141632);              // spans R1+R2
    float*    rsa   = (float*)(ws + 201424896);
    ushort_t* wp    = (ushort_t*)(ws + 203785216);

    ushort_t* w_h    = wp;                 // weight  65,536
    ushort_t* w_l    = wp + 65536;
    ushort_t* wqkv_h = wp + 131072;        // Wqkv   589,824 (head-interleaved, hi only)
    ushort_t* wo_h   = wp + 1310720;       // Wo     196,608 (hi only)
    ushort_t* fc1_h  = wp + 1703936;       // fc1    262,144 (hi only)
    ushort_t* fc2_h  = wp + 2228224;       // fc2    262,144 (hi only)

    pack2_k<<<256,  256, 0, stream>>>(weight, w_h,    w_l,    65536);
    wqkv_pack_k<<<2304, 256, 0, stream>>>(Wqkv, wqkv_h);
    pack2_k<<<768,  256, 0, stream>>>(Wo,     wo_h,   nullptr, 196608);
    pack2_k<<<1024, 256, 0, stream>>>(fc1_w,  fc1_h,  nullptr, 262144);
    pack2_k<<<1024, 256, 0, stream>>>(fc2_w,  fc2_h,  nullptr, 262144);
    // pack x hi-only into zh (consumed by embed GEMM, then ln_k overwrites)
    pack2_k<<<65536, 256, 0, stream>>>(x, zh, nullptr, AA * BB * CC);

    row0_k<<<AA, 256, 0, stream>>>(out, cls, bias);
    // embed: out[i,1+j,:] = x[i,j,:] @ weight^T + bias  (2-term: full weight precision)
    mm_k<0,1><<<4 * 1024, 64, 0, stream>>>(zh, nullptr, w_h, w_l, out, nullptr, bias,
                                           AA * BB, CC, CC, 4, F_ROWMAP | F_BIAS2D);

    const int MT = (NROWS + 63) / 64;   // 1025
    for (int a = 0; a < NBLK; ++a) {
        const size_t aw = (size_t)a * 196608;   // per-layer Wqkv stride
        ln_k<<<NROWS / 4, 256, 0, stream>>>(out, zh, ln1_g, ln1_b);
        // fused qkv (1-term): qk tiles -> rsa in-register (fp32), v tiles -> bf16 vbuf
        mm_k<0,0><<<12 * MT, 64, 0, stream>>>(zh, nullptr, wqkv_h + aw, nullptr,
                                              rsa, vbuf, nullptr,
                                              NROWS, CC, 768, 12, F_QKV);
        cumsum1_k<<<1024, 256, 0, stream>>>(vbuf, rsa, tot);
        cumsum2_k<<<1056, 256, 0, stream>>>(vbuf, rsa, tot, imh);
        // savespace += im @ Wo^T  (1-term: im bf16 x Wo hi)
        mm_k<0,0><<<4 * MT, 64, 0, stream>>>(imh, nullptr, wo_h + (size_t)a * 65536,
                                             nullptr, out, nullptr, nullptr,
                                             NROWS, CC, CC, 4, F_RESID);
        ln_k<<<NROWS / 4, 256, 0, stream>>>(out, zh, ln2_g, ln2_b);
        // h = gelu(z @ fc1^T + b) -> bf16 hbuf  (1-term)
        mm_k<0,0><<<16 * MT, 64, 0, stream>>>(zh, nullptr, fc1_h, nullptr, hbuf, nullptr, fc1_b,
                                              NROWS, CC, FFN, 16, F_BIAS1D | F_GELU | F_OUTB16);
        // savespace += h @ fc2^T + b  (1-term)
        mm_k<0,0><<<4 * MT, 64, 0, stream>>>(hbuf, nullptr, fc2_h, nullptr, out, nullptr, fc2_b,
                                             NROWS, FFN, CC, 4, F_BIAS1D | F_RESID);
    }
}

// Round 30
// 1115.784 us; speedup vs baseline: 1.0102x; 1.0039x over previous
//
#include <hip/hip_runtime.h>
#include <math.h>

#define AA 32
#define BB 2048
#define BP1 2049
#define CC 256
#define NROWS (AA * BP1)          // 65568
#define NBLK 3
#define FFN 1024

typedef unsigned int uint;
typedef unsigned short ushort_t;
typedef __attribute__((ext_vector_type(4))) float f32x4;
typedef __attribute__((ext_vector_type(8))) short short8;

// epilogue flag bits for mm_k (wave-uniform runtime flags)
#define F_ROWMAP 2
#define F_BIAS2D 4
#define F_BIAS1D 8
#define F_GELU   16
#define F_RESID  32
#define F_OUTB16 64
#define F_QKV    128

__device__ __forceinline__ float bf2f(ushort_t u) {
    return __uint_as_float(((uint)u) << 16);
}
__device__ __forceinline__ ushort_t f2b(float x) {   // fp32 -> bf16 RNE
    uint u = __float_as_uint(x);
    u += 0x7fff + ((u >> 16) & 1);
    return (ushort_t)(u >> 16);
}
// pack two fp32 -> {lo: bf16(a), hi: bf16(b)} in ONE instruction (gfx950)
__device__ __forceinline__ uint cvtpk(float a, float b) {
    uint r;
    asm("v_cvt_pk_bf16_f32 %0, %1, %2" : "=v"(r) : "v"(a), "v"(b));
    return r;
}

// global -> LDS direct 16B load
typedef const uint __attribute__((address_space(1)))* gas_t;
typedef uint __attribute__((address_space(3)))* las_t;
__device__ __forceinline__ void gload16(const ushort_t* g, const short* l) {
    __builtin_amdgcn_global_load_lds(
        reinterpret_cast<gas_t>(reinterpret_cast<uintptr_t>(g)),
        reinterpret_cast<las_t>(static_cast<uint>(reinterpret_cast<uintptr_t>(l))),
        16, 0, 0);
}

// ---------------- fp32 -> bf16 planes (lo plane optional) ----------------
__global__ __launch_bounds__(256) void pack2_k(const float* __restrict__ src,
                                               ushort_t* __restrict__ dh,
                                               ushort_t* __restrict__ dl, int n) {
    int i = blockIdx.x * 256 + threadIdx.x;
    if (i < n) {
        float v = src[i];
        ushort_t h = f2b(v);
        dh[i] = h;
        if (dl) dl[i] = f2b(v - bf2f(h));
    }
}

// ---------------- Wqkv pack with head-interleaved q/k rows (hi plane only) ----------------
// dst row order per layer: [h0q(32) h0k(32) ... h7q h7k, v(256)]
__global__ __launch_bounds__(256) void wqkv_pack_k(const float* __restrict__ src,
                                                   ushort_t* __restrict__ dh) {
    int i = blockIdx.x * 256 + threadIdx.x;      // 589,824 total
    if (i >= 589824) return;
    int c = i & 255;
    int rr = (i >> 8) % 768;
    int a = i / (768 * 256);
    int srcrow;
    if (rr < 512) {
        int head = rr >> 6, half = (rr >> 5) & 1, d = rr & 31;
        srcrow = half * 256 + head * 32 + d;
    } else {
        srcrow = rr;
    }
    dh[i] = f2b(src[((size_t)a * 768 + srcrow) * 256 + c]);
}

// ---------------- row 0 of each batch: cls + bias ----------------
__global__ __launch_bounds__(256) void row0_k(float* __restrict__ out,
                                              const float* __restrict__ cls,
                                              const float* __restrict__ bias) {
    int i = blockIdx.x, t = threadIdx.x;
    size_t o = (size_t)i * BP1 * CC + t;
    out[o] = cls[i * CC + t] + bias[o];
}

// ---------------- layernorm f32 -> bf16 plane (hi only, cvt_pk packed) ----------------
__global__ __launch_bounds__(256) void ln_k(const float* __restrict__ in,
                                            ushort_t* __restrict__ zh,
                                            const float* __restrict__ g, const float* __restrict__ b) {
    int row = blockIdx.x * 4 + (threadIdx.x >> 6);
    int lane = threadIdx.x & 63;
    const float4 v = *reinterpret_cast<const float4*>(in + (size_t)row * CC + lane * 4);
    float s = v.x + v.y + v.z + v.w;
    float sq = v.x * v.x + v.y * v.y + v.z * v.z + v.w * v.w;
    #pragma unroll
    for (int m = 1; m < 64; m <<= 1) { s += __shfl_xor(s, m); sq += __shfl_xor(sq, m); }
    float mu = s * (1.0f / CC);
    float var = sq * (1.0f / CC) - mu * mu;
    float rs = rsqrtf(var + 1e-5f);
    const float4 gg = *reinterpret_cast<const float4*>(g + lane * 4);
    const float4 bb = *reinterpret_cast<const float4*>(b + lane * 4);
    float o0 = (v.x - mu) * rs * gg.x + bb.x;
    float o1 = (v.y - mu) * rs * gg.y + bb.y;
    float o2 = (v.z - mu) * rs * gg.z + bb.z;
    float o3 = (v.w - mu) * rs * gg.w + bb.w;
    uint2 u;
    u.x = cvtpk(o0, o1);
    u.y = cvtpk(o2, o3);
    *reinterpret_cast<uint2*>(zh + (size_t)row * CC + lane * 4) = u;
}

// ---------------- cumsum pass 1: per-chunk totals of rsa*v (v bf16, 32 x 64 rows) ----------------
__global__ __launch_bounds__(256) void cumsum1_k(const ushort_t* __restrict__ v,
                                                 const float* __restrict__ rsa,
                                                 float* __restrict__ tot) {
    int bi = blockIdx.x >> 5, ch = blockIdx.x & 31, c = threadIdx.x;
    int h = c >> 5;
    size_t row0 = (size_t)bi * BP1 + ch * 64;
    float s = 0.f;
    for (int j = 0; j < 64; ++j)
        s += bf2f(v[(row0 + j) * CC + c]) * rsa[(row0 + j) * 8 + h];
    tot[((size_t)bi * 32 + ch) * CC + c] = s;
}

// ---------------- cumsum pass 2: scan rsa*v + offset -> im hi plane only ----------------
__global__ __launch_bounds__(256) void cumsum2_k(const ushort_t* __restrict__ v,
                                                 const float* __restrict__ rsa,
                                                 const float* __restrict__ tot,
                                                 ushort_t* __restrict__ ph) {
    int bi = blockIdx.x / 33, ch = blockIdx.x - bi * 33, c = threadIdx.x;
    int h = c >> 5;
    if (ch == 32) {
        size_t row = (size_t)bi * BP1 + BB;
        float val = bf2f(v[row * CC + c]) * rsa[row * 8 + h];
        ph[row * CC + c] = f2b(val);
        return;
    }
    float s = 0.f;
    for (int q = 0; q < ch; ++q) s += tot[((size_t)bi * 32 + q) * CC + c];
    size_t row0 = (size_t)bi * BP1 + ch * 64;
    for (int j = 0; j < 64; ++j) {
        size_t row = row0 + j;
        s += bf2f(v[row * CC + c]) * rsa[row * 8 + h];
        ph[row * CC + c] = f2b(s);
    }
}

// ---------------- split-bf16 MFMA GEMM, 1-wave 64x64 tile (hardened sync) ----------------
// Out(MxN) = A(MxK) * W(NxK)^T ; 1-D grid = NT*MT (MT = M/64, NT = NC/64).
// Sync via __syncthreads() (full vmcnt/lgkmcnt drain + barrier; barrier is free for
// a 1-wave block) — replaces hand-rolled vmcnt asm after a rare post-timing
// divergence in round 29 (suspected LDS ordering hazard under contention).
// MFMA operand-swapped: lane holds Out[row = m0+i*16+(l&15)][4 consecutive cols].
template<int ALO, int WLO>
__global__ __launch_bounds__(64) void mm_k(const ushort_t* __restrict__ Ah_g,
                                           const ushort_t* __restrict__ Al_g,
                                           const ushort_t* __restrict__ Bh_g,
                                           const ushort_t* __restrict__ Bl_g,
                                           void* __restrict__ Op,
                                           void* __restrict__ Op2,
                                           const float* __restrict__ bias,
                                           int M, int K, int NC, int NT, int flags) {
    __shared__ __align__(16) short As_h[2048];
    __shared__ __align__(16) short As_l[ALO ? 2048 : 8];
    __shared__ __align__(16) short Bs_h[2048];
    __shared__ __align__(16) short Bs_l[WLO ? 2048 : 8];
    const int l = threadIdx.x;                     // 0..63 (one wave)

    // XCD-bijective block swizzle (m204)
    const int nwg = gridDim.x;
    const int q8 = nwg >> 3, r8 = nwg & 7;
    const int xcd = blockIdx.x & 7, ii = blockIdx.x >> 3;
    const int wgid = (xcd < r8 ? xcd * (q8 + 1) : r8 * (q8 + 1) + (xcd - r8) * q8) + ii;
    const int nt = wgid % NT, mt = wgid / NT;
    const int n0 = nt * 64, m0 = mt * 64;

    // staging: chunk c covers rows c*16 + (l>>2), cols (l&3)*8 (1 KB per chunk)
    const int sc = (l & 3) * 8;
    const int lr = l >> 2;
    size_t aoff[4], boff[4];
    #pragma unroll
    for (int c = 0; c < 4; ++c) {
        int ra = m0 + c * 16 + lr; if (ra >= M) ra = M - 1;
        aoff[c] = (size_t)ra * K + sc;
        boff[c] = (size_t)(n0 + c * 16 + lr) * K + sc;
    }

    f32x4 acc[4][4];
    #pragma unroll
    for (int i = 0; i < 4; ++i)
        #pragma unroll
        for (int j = 0; j < 4; ++j) acc[i][j] = (f32x4)(0.0f);

    for (int k0 = 0; k0 < K; k0 += 32) {
        #pragma unroll
        for (int c = 0; c < 4; ++c) {
            gload16(Ah_g + aoff[c] + k0, &As_h[c * 512]);
            if (ALO) gload16(Al_g + aoff[c] + k0, &As_l[c * 512]);
            gload16(Bh_g + boff[c] + k0, &Bs_h[c * 512]);
            if (WLO) gload16(Bl_g + boff[c] + k0, &Bs_l[c * 512]);
        }
        __syncthreads();                           // full drain: staged data visible
        short8 ah[4], al[4], bh[4], bl[4];
        #pragma unroll
        for (int i = 0; i < 4; ++i) {
            int ro = (i * 16 + (l & 15)) * 32 + (l >> 4) * 8;
            ah[i] = *reinterpret_cast<const short8*>(&As_h[ro]);
            if (ALO) al[i] = *reinterpret_cast<const short8*>(&As_l[ro]);
        }
        #pragma unroll
        for (int j = 0; j < 4; ++j) {
            int ro = (j * 16 + (l & 15)) * 32 + (l >> 4) * 8;
            bh[j] = *reinterpret_cast<const short8*>(&Bs_h[ro]);
            if (WLO) bl[j] = *reinterpret_cast<const short8*>(&Bs_l[ro]);
        }
        // operand-swapped MFMA: D = B-frag x A-frag
        __builtin_amdgcn_s_setprio(1);
        #pragma unroll
        for (int i = 0; i < 4; ++i)
            #pragma unroll
            for (int j = 0; j < 4; ++j) {
                acc[i][j] = __builtin_amdgcn_mfma_f32_16x16x32_bf16(bh[j], ah[i], acc[i][j], 0, 0, 0);
                if (WLO)
                    acc[i][j] = __builtin_amdgcn_mfma_f32_16x16x32_bf16(bl[j], ah[i], acc[i][j], 0, 0, 0);
                if (ALO)
                    acc[i][j] = __builtin_amdgcn_mfma_f32_16x16x32_bf16(bh[j], al[i], acc[i][j], 0, 0, 0);
            }
        __builtin_amdgcn_s_setprio(0);
        __syncthreads();                           // ds_reads retired before next stage
    }

    // ---- F_QKV epilogue (swapped layout) ----
    if (flags & F_QKV) {
        const int cb0 = n0;                        // 64-wide tile = one head's q|k
        if (cb0 < 512) {
            float* rsaO = reinterpret_cast<float*>(Op);
            const int head = cb0 >> 6;
            #pragma unroll
            for (int i = 0; i < 4; ++i) {
                int row = m0 + i * 16 + (l & 15);
                float p = 0.f;
                #pragma unroll
                for (int j = 0; j < 2; ++j)
                    #pragma unroll
                    for (int r = 0; r < 4; ++r)
                        p += acc[i][j][r] * acc[i][j + 2][r];
                p += __shfl_xor(p, 16);
                p += __shfl_xor(p, 32);
                if (l < 16 && row < M)
                    rsaO[(size_t)row * 8 + head] = p * 0.17677669529663689f;
            }
        } else {                                   // v tile -> bf16 vbuf (uint2 = 4 bf16)
            ushort_t* vO = reinterpret_cast<ushort_t*>(Op2);
            #pragma unroll
            for (int i = 0; i < 4; ++i) {
                int row = m0 + i * 16 + (l & 15);
                if (row >= M) continue;
                #pragma unroll
                for (int j = 0; j < 4; ++j) {
                    int colb = cb0 + j * 16 + (l >> 4) * 4 - 512;
                    uint2 u;
                    u.x = cvtpk(acc[i][j][0], acc[i][j][1]);
                    u.y = cvtpk(acc[i][j][2], acc[i][j][3]);
                    *reinterpret_cast<uint2*>(vO + (size_t)row * 256 + colb) = u;
                }
            }
        }
        return;
    }

    // ---- general epilogue ----
    #pragma unroll
    for (int i = 0; i < 4; ++i) {
        int row = m0 + i * 16 + (l & 15);
        if (row >= M) continue;
        size_t g = (flags & F_ROWMAP) ? ((size_t)(row >> 11) * BP1 + 1 + (row & 2047))
                                     : (size_t)row;
        #pragma unroll
        for (int j = 0; j < 4; ++j) {
            int col0 = n0 + j * 16 + (l >> 4) * 4;
            float4 v4 = make_float4(acc[i][j][0], acc[i][j][1], acc[i][j][2], acc[i][j][3]);
            if (flags & F_BIAS1D) {
                const float4 b4 = *reinterpret_cast<const float4*>(bias + col0);
                v4.x += b4.x; v4.y += b4.y; v4.z += b4.z; v4.w += b4.w;
            }
            if (flags & F_BIAS2D) {
                const float4 b4 = *reinterpret_cast<const float4*>(bias + g * (size_t)NC + col0);
                v4.x += b4.x; v4.y += b4.y; v4.z += b4.z; v4.w += b4.w;
            }
            if (flags & F_GELU) {   // tanh-form GELU, fast rcp
                float z0 = v4.x * (1.595769122f + 0.071354816f * v4.x * v4.x);
                float z1 = v4.y * (1.595769122f + 0.071354816f * v4.y * v4.y);
                float z2 = v4.z * (1.595769122f + 0.071354816f * v4.z * v4.z);
                float z3 = v4.w * (1.595769122f + 0.071354816f * v4.w * v4.w);
                v4.x *= __builtin_amdgcn_rcpf(1.0f + __expf(-z0));
                v4.y *= __builtin_amdgcn_rcpf(1.0f + __expf(-z1));
                v4.z *= __builtin_amdgcn_rcpf(1.0f + __expf(-z2));
                v4.w *= __builtin_amdgcn_rcpf(1.0f + __expf(-z3));
            }
            size_t oi = g * (size_t)NC + col0;
            if (flags & F_OUTB16) {
                uint2 u;
                u.x = cvtpk(v4.x, v4.y);
                u.y = cvtpk(v4.z, v4.w);
                *reinterpret_cast<uint2*>(reinterpret_cast<ushort_t*>(Op) + oi) = u;
            } else {
                float* O = reinterpret_cast<float*>(Op) + oi;
                if (flags & F_RESID) {
                    const float4 o4 = *reinterpret_cast<const float4*>(O);
                    v4.x += o4.x; v4.y += o4.y; v4.z += o4.z; v4.w += o4.w;
                }
                *reinterpret_cast<float4*>(O) = v4;
            }
        }
    }
}

// ---------------- launch ----------------
extern "C" void kernel_launch(void* const* d_in, const int* in_sizes, int n_in,
                              void* d_out, int out_size, void* d_ws, size_t ws_size,
                              hipStream_t stream) {
    const float* x      = (const float*)d_in[0];
    const float* weight = (const float*)d_in[1];
    const float* bias   = (const float*)d_in[2];
    const float* cls    = (const float*)d_in[3];
    const float* Wqkv   = (const float*)d_in[4];
    const float* Wo     = (const float*)d_in[5];
    const float* ln1_g  = (const float*)d_in[6];
    const float* ln1_b  = (const float*)d_in[7];
    const float* ln2_g  = (const float*)d_in[8];
    const float* ln2_b  = (const float*)d_in[9];
    const float* fc1_w  = (const float*)d_in[10];
    const float* fc1_b  = (const float*)d_in[11];
    const float* fc2_w  = (const float*)d_in[12];
    const float* fc2_b  = (const float*)d_in[13];
    float* out = (float*)d_out;

    // ---- workspace (high-water 209,290,240 B — proven rounds 7-29) ----
    char* ws = (char*)d_ws;
    ushort_t* zh    = (ushort_t*)(ws + 0);
    float*    tot   = (float*)(ws + 33570816);
    ushort_t* vbuf  = (ushort_t*)(ws + 67141632);
    ushort_t* imh   = (ushort_t*)(ws + 134283264);
    ushort_t* hbuf  = (ushort_t*)(ws + 67141632);              // spans R1+R2
    float*    rsa   = (float*)(ws + 201424896);
    ushort_t* wp    = (ushort_t*)(ws + 203785216);

    ushort_t* w_h    = wp;                 // weight  65,536
    ushort_t* w_l    = wp + 65536;
    ushort_t* wqkv_h = wp + 131072;        // Wqkv   589,824 (head-interleaved, hi only)
    ushort_t* wo_h   = wp + 1310720;       // Wo     196,608 (hi only)
    ushort_t* fc1_h  = wp + 1703936;       // fc1    262,144 (hi only)
    ushort_t* fc2_h  = wp + 2228224;       // fc2    262,144 (hi only)

    pack2_k<<<256,  256, 0, stream>>>(weight, w_h,    w_l,    65536);
    wqkv_pack_k<<<2304, 256, 0, stream>>>(Wqkv, wqkv_h);
    pack2_k<<<768,  256, 0, stream>>>(Wo,     wo_h,   nullptr, 196608);
    pack2_k<<<1024, 256, 0, stream>>>(fc1_w,  fc1_h,  nullptr, 262144);
    pack2_k<<<1024, 256, 0, stream>>>(fc2_w,  fc2_h,  nullptr, 262144);
    // pack x hi-only into zh (consumed by embed GEMM, then ln_k overwrites)
    pack2_k<<<65536, 256, 0, stream>>>(x, zh, nullptr, AA * BB * CC);

    row0_k<<<AA, 256, 0, stream>>>(out, cls, bias);
    // embed: out[i,1+j,:] = x[i,j,:] @ weight^T + bias  (2-term: full weight precision)
    mm_k<0,1><<<4 * 1024, 64, 0, stream>>>(zh, nullptr, w_h, w_l, out, nullptr, bias,
                                           AA * BB, CC, CC, 4, F_ROWMAP | F_BIAS2D);

    const int MT = (NROWS + 63) / 64;   // 1025
    for (int a = 0; a < NBLK; ++a) {
        const size_t aw = (size_t)a * 196608;   // per-layer Wqkv stride
        ln_k<<<NROWS / 4, 256, 0, stream>>>(out, zh, ln1_g, ln1_b);
        // fused qkv (1-term): qk tiles -> rsa in-register (fp32), v tiles -> bf16 vbuf
        mm_k<0,0><<<12 * MT, 64, 0, stream>>>(zh, nullptr, wqkv_h + aw, nullptr,
                                              rsa, vbuf, nullptr,
                                              NROWS, CC, 768, 12, F_QKV);
        cumsum1_k<<<1024, 256, 0, stream>>>(vbuf, rsa, tot);
        cumsum2_k<<<1056, 256, 0, stream>>>(vbuf, rsa, tot, imh);
        // savespace += im @ Wo^T  (1-term: im bf16 x Wo hi)
        mm_k<0,0><<<4 * MT, 64, 0, stream>>>(imh, nullptr, wo_h + (size_t)a * 65536,
                                             nullptr, out, nullptr, nullptr,
                                             NROWS, CC, CC, 4, F_RESID);
        ln_k<<<NROWS / 4, 256, 0, stream>>>(out, zh, ln2_g, ln2_b);
        // h = gelu(z @ fc1^T + b) -> bf16 hbuf  (1-term)
        mm_k<0,0><<<16 * MT, 64, 0, stream>>>(zh, nullptr, fc1_h, nullptr, hbuf, nullptr, fc1_b,
                                              NROWS, CC, FFN, 16, F_BIAS1D | F_GELU | F_OUTB16);
        // savespace += h @ fc2^T + b  (1-term)
        mm_k<0,0><<<4 * MT, 64, 0, stream>>>(hbuf, nullptr, fc2_h, nullptr, out, nullptr, fc2_b,
                                             NROWS, FFN, CC, 4, F_BIAS1D | F_RESID);
    }
}